// Round 2
// baseline (342.462 us; speedup 1.0000x reference)
//
#include <hip/hip_runtime.h>
#include <math.h>

#define N_GAUSS 2048
#define IMG_H 256
#define IMG_W 256
#define NPIX (IMG_H * IMG_W)
#define EPS 1e-4f

// Per-gaussian parameters, padded to 32B. Loaded via wave-uniform (scalar) path.
struct GParam {
    float x, y;    // center
    float c, s;    // cos(rot), sin(rot) -- fp32-rounded from double trig
    float sx, sy;  // inverse std-devs
    float pad0, pad1;
};

__global__ void prep_kernel(const float* __restrict__ xy,
                            const float* __restrict__ scale,
                            const float* __restrict__ rot,
                            GParam* __restrict__ gp) {
    int g = blockIdx.x * blockDim.x + threadIdx.x;
    if (g >= N_GAUSS) return;
    GParam o;
    o.x  = xy[2 * g + 0];
    o.y  = xy[2 * g + 1];
    o.sx = scale[2 * g + 0];
    o.sy = scale[2 * g + 1];
    double r = (double)rot[g];
    // Correctly-rounded fp32 sin/cos (match numpy's libm within <=1 ulp).
    o.c = (float)cos(r);
    o.s = (float)sin(r);
    o.pad0 = 0.f; o.pad1 = 0.f;
    gp[g] = o;
}

__launch_bounds__(256)
__global__ void splat_kernel(const GParam* __restrict__ gp,
                             const float* __restrict__ feat,
                             float* __restrict__ out) {
    int p = blockIdx.x * blockDim.x + threadIdx.x;
    // (i + 0.5) / 256 is exact as (i + 0.5) * 2^-8.
    float px = ((p & (IMG_W - 1)) + 0.5f) * (1.0f / IMG_W);
    float py = ((p >> 8) + 0.5f) * (1.0f / IMG_H);

    // 8 smallest t (ascending) and their gaussian indices.
    float v0 = INFINITY, v1 = INFINITY, v2 = INFINITY, v3 = INFINITY;
    float v4 = INFINITY, v5 = INFINITY, v6 = INFINITY, v7 = INFINITY;
    int   i0 = 0, i1 = 0, i2 = 0, i3 = 0, i4 = 0, i5 = 0, i6 = 0, i7 = 0;

#pragma unroll 4
    for (int g = 0; g < N_GAUSS; ++g) {
        GParam cf = gp[g];  // wave-uniform -> scalar loads
        // Bit-exact replication of the numpy reference arithmetic (fp32,
        // one rounding per op, NO fma contraction):
        //   dx = px - x; dy = py - y
        //   lx = dx*c + dy*s;  ly = (-dx)*s + dy*c
        //   t  = (lx*sx)^2 + (ly*sy)^2
        float dx = __fsub_rn(px, cf.x);
        float dy = __fsub_rn(py, cf.y);
        float lx = __fadd_rn(__fmul_rn(dx, cf.c), __fmul_rn(dy, cf.s));
        float ly = __fadd_rn(__fmul_rn(-dx, cf.s), __fmul_rn(dy, cf.c));
        float a  = __fmul_rn(lx, cf.sx);
        float b  = __fmul_rn(ly, cf.sy);
        float t  = __fadd_rn(__fmul_rn(a, a), __fmul_rn(b, b));
        if (t < v7) {
            // Branchless sorted-insert ladder; strict < keeps lowest index on
            // ties, matching top_k's stable ordering.
            const bool c0 = t < v0, c1 = t < v1, c2 = t < v2, c3 = t < v3;
            const bool c4 = t < v4, c5 = t < v5, c6 = t < v6;
            v7 = c6 ? v6 : t;              i7 = c6 ? i6 : g;
            v6 = c6 ? (c5 ? v5 : t) : v6;  i6 = c6 ? (c5 ? i5 : g) : i6;
            v5 = c5 ? (c4 ? v4 : t) : v5;  i5 = c5 ? (c4 ? i4 : g) : i5;
            v4 = c4 ? (c3 ? v3 : t) : v4;  i4 = c4 ? (c3 ? i3 : g) : i4;
            v3 = c3 ? (c2 ? v2 : t) : v3;  i3 = c3 ? (c2 ? i2 : g) : i3;
            v2 = c2 ? (c1 ? v1 : t) : v2;  i2 = c2 ? (c1 ? i1 : g) : i2;
            v1 = c1 ? (c0 ? v0 : t) : v1;  i1 = c1 ? (c0 ? i0 : g) : i1;
            v0 = c0 ? t : v0;              i0 = c0 ? g : i0;
        }
    }

    // Weights: w = exp(-0.5 * t). -0.5*t is exact (power of two).
    float w0 = expf(-0.5f * v0), w1 = expf(-0.5f * v1);
    float w2 = expf(-0.5f * v2), w3 = expf(-0.5f * v3);
    float w4 = expf(-0.5f * v4), w5 = expf(-0.5f * v5);
    float w6 = expf(-0.5f * v6), w7 = expf(-0.5f * v7);
    // Sum in descending-weight order, matching the reference's top_k order.
    float sum = w0 + w1 + w2 + w3 + w4 + w5 + w6 + w7;
    float inv = 1.0f / (sum + EPS);

    float oc0 = 0.f, oc1 = 0.f, oc2 = 0.f;
#define ACC(K)                                                  \
    {                                                           \
        float al = w##K * inv;                                  \
        const float* f = feat + 3 * i##K;                       \
        oc0 = fmaf(al, f[0], oc0);                              \
        oc1 = fmaf(al, f[1], oc1);                              \
        oc2 = fmaf(al, f[2], oc2);                              \
    }
    ACC(0) ACC(1) ACC(2) ACC(3) ACC(4) ACC(5) ACC(6) ACC(7)
#undef ACC

    out[p]            = oc0;
    out[p + NPIX]     = oc1;
    out[p + 2 * NPIX] = oc2;
}

extern "C" void kernel_launch(void* const* d_in, const int* in_sizes, int n_in,
                              void* d_out, int out_size, void* d_ws, size_t ws_size,
                              hipStream_t stream) {
    const float* xy    = (const float*)d_in[0];
    const float* scale = (const float*)d_in[1];
    const float* rot   = (const float*)d_in[2];
    const float* feat  = (const float*)d_in[3];
    float* out = (float*)d_out;
    GParam* gp = (GParam*)d_ws;  // 2048 * 32B = 64 KB scratch

    prep_kernel<<<(N_GAUSS + 255) / 256, 256, 0, stream>>>(xy, scale, rot, gp);
    splat_kernel<<<NPIX / 256, 256, 0, stream>>>(gp, feat, out);
}

// Round 3
// 143.850 us; speedup vs baseline: 2.3807x; 2.3807x over previous
//
#include <hip/hip_runtime.h>
#include <math.h>

#define N_GAUSS 2048
#define IMG_H 256
#define IMG_W 256
#define NPIX (IMG_H * IMG_W)
#define EPS 1e-4f

#define SPLIT 8                     // gaussian chunks per pixel
#define CHUNK (N_GAUSS / SPLIT)     // 256 gaussians per chunk
#define PIXB 128                    // pixels per block
#define NTHREADS (PIXB * SPLIT)     // 1024 threads / block

// Per-gaussian parameters, 32B for aligned s_load_dwordx8.
struct GParam {
    float x, y;    // center
    float c, s;    // cos(rot), sin(rot) -- fp32-rounded from double trig
    float sx, sy;  // inverse std-devs
    float pad0, pad1;
};

__global__ void prep_kernel(const float* __restrict__ xy,
                            const float* __restrict__ scale,
                            const float* __restrict__ rot,
                            GParam* __restrict__ gp) {
    int g = blockIdx.x * blockDim.x + threadIdx.x;
    if (g >= N_GAUSS) return;
    GParam o;
    o.x  = xy[2 * g + 0];
    o.y  = xy[2 * g + 1];
    o.sx = scale[2 * g + 0];
    o.sy = scale[2 * g + 1];
    double r = (double)rot[g];
    o.c = (float)cos(r);   // correctly-rounded fp32 trig (numpy-matching)
    o.s = (float)sin(r);
    o.pad0 = 0.f; o.pad1 = 0.f;
    gp[g] = o;
}

// Bit-exact reference arithmetic + strict-< sorted-insert ladder.
// Strict < => equal-t keeps the earlier-inserted (lower index) entry ahead,
// matching jax/np top_k stable ordering.
#define LADDER(T, G)                                                     \
    if ((T) < v7) {                                                      \
        const bool c0 = (T) < v0, c1 = (T) < v1, c2 = (T) < v2;          \
        const bool c3 = (T) < v3, c4 = (T) < v4, c5 = (T) < v5;          \
        const bool c6 = (T) < v6;                                        \
        v7 = c6 ? v6 : (T);            i7 = c6 ? i6 : (G);               \
        v6 = c6 ? (c5 ? v5 : (T)) : v6; i6 = c6 ? (c5 ? i5 : (G)) : i6;  \
        v5 = c5 ? (c4 ? v4 : (T)) : v5; i5 = c5 ? (c4 ? i4 : (G)) : i5;  \
        v4 = c4 ? (c3 ? v3 : (T)) : v4; i4 = c4 ? (c3 ? i3 : (G)) : i4;  \
        v3 = c3 ? (c2 ? v2 : (T)) : v3; i3 = c3 ? (c2 ? i2 : (G)) : i3;  \
        v2 = c2 ? (c1 ? v1 : (T)) : v2; i2 = c2 ? (c1 ? i1 : (G)) : i2;  \
        v1 = c1 ? (c0 ? v0 : (T)) : v1; i1 = c1 ? (c0 ? i0 : (G)) : i1;  \
        v0 = c0 ? (T) : v0;            i0 = c0 ? (G) : i0;               \
    }

#define PROC(CF, G)                                                      \
    {                                                                    \
        float dx = __fsub_rn(px, (CF).x);                                \
        float dy = __fsub_rn(py, (CF).y);                                \
        float lx = __fadd_rn(__fmul_rn(dx, (CF).c), __fmul_rn(dy, (CF).s)); \
        float ly = __fadd_rn(__fmul_rn(-dx, (CF).s), __fmul_rn(dy, (CF).c)); \
        float a  = __fmul_rn(lx, (CF).sx);                               \
        float b  = __fmul_rn(ly, (CF).sy);                               \
        float t  = __fadd_rn(__fmul_rn(a, a), __fmul_rn(b, b));          \
        LADDER(t, (G))                                                   \
    }

__launch_bounds__(NTHREADS)
__global__ void splat_kernel(const GParam* __restrict__ gp,
                             const float* __restrict__ feat,
                             float* __restrict__ out) {
    // SoA-transposed merge buffers: lane stride 4B/2B -> conflict-free.
    __shared__ float          lt[SPLIT][8][PIXB];  // 32 KB
    __shared__ unsigned short li[SPLIT][8][PIXB];  // 16 KB

    const int tid   = threadIdx.x;
    const int pix   = tid & (PIXB - 1);
    const int chunk = tid >> 7;              // log2(PIXB)
    const int p     = blockIdx.x * PIXB + pix;
    const float px = ((p & (IMG_W - 1)) + 0.5f) * (1.0f / IMG_W);
    const float py = ((p >> 8) + 0.5f) * (1.0f / IMG_H);

    float v0 = INFINITY, v1 = INFINITY, v2 = INFINITY, v3 = INFINITY;
    float v4 = INFINITY, v5 = INFINITY, v6 = INFINITY, v7 = INFINITY;
    int   i0 = 0, i1 = 0, i2 = 0, i3 = 0, i4 = 0, i5 = 0, i6 = 0, i7 = 0;

    const int gbase = chunk * CHUNK;
    const GParam* gptr = gp + gbase;

    // 2-deep register prefetch pipeline (wave-uniform index -> s_load path;
    // two loads in flight under each 2-gaussian compute block).
    GParam c0 = gptr[0];
    GParam c1 = gptr[1];
    for (int j = 0; j < CHUNK - 2; j += 2) {
        GParam n0 = gptr[j + 2];
        GParam n1 = gptr[j + 3];
        PROC(c0, gbase + j)
        PROC(c1, gbase + j + 1)
        c0 = n0; c1 = n1;
    }
    PROC(c0, gbase + CHUNK - 2)
    PROC(c1, gbase + CHUNK - 1)

    // Publish this chunk's sorted top-8.
    lt[chunk][0][pix] = v0; li[chunk][0][pix] = (unsigned short)i0;
    lt[chunk][1][pix] = v1; li[chunk][1][pix] = (unsigned short)i1;
    lt[chunk][2][pix] = v2; li[chunk][2][pix] = (unsigned short)i2;
    lt[chunk][3][pix] = v3; li[chunk][3][pix] = (unsigned short)i3;
    lt[chunk][4][pix] = v4; li[chunk][4][pix] = (unsigned short)i4;
    lt[chunk][5][pix] = v5; li[chunk][5][pix] = (unsigned short)i5;
    lt[chunk][6][pix] = v6; li[chunk][6][pix] = (unsigned short)i6;
    lt[chunk][7][pix] = v7; li[chunk][7][pix] = (unsigned short)i7;

    __syncthreads();

    if (chunk == 0) {
        // Merge 8 sorted lists. Processing in ascending chunk (= ascending
        // gaussian index) order with the same strict-< ladder reproduces the
        // single-stream selection and ordering exactly.
        v0 = INFINITY; v1 = INFINITY; v2 = INFINITY; v3 = INFINITY;
        v4 = INFINITY; v5 = INFINITY; v6 = INFINITY; v7 = INFINITY;
        i0 = 0; i1 = 0; i2 = 0; i3 = 0; i4 = 0; i5 = 0; i6 = 0; i7 = 0;
        for (int c = 0; c < SPLIT; ++c) {
#pragma unroll
            for (int k = 0; k < 8; ++k) {
                float t = lt[c][k][pix];
                int   g = (int)li[c][k][pix];
                LADDER(t, g)
            }
        }

        // Weights: w = exp(-0.5*t); -0.5*t exact (power of two).
        float w0 = expf(-0.5f * v0), w1 = expf(-0.5f * v1);
        float w2 = expf(-0.5f * v2), w3 = expf(-0.5f * v3);
        float w4 = expf(-0.5f * v4), w5 = expf(-0.5f * v5);
        float w6 = expf(-0.5f * v6), w7 = expf(-0.5f * v7);
        float sum = w0 + w1 + w2 + w3 + w4 + w5 + w6 + w7;
        float inv = 1.0f / (sum + EPS);

        float oc0 = 0.f, oc1 = 0.f, oc2 = 0.f;
#define ACC(K)                                                  \
        {                                                       \
            float al = w##K * inv;                              \
            const float* f = feat + 3 * i##K;                   \
            oc0 = fmaf(al, f[0], oc0);                          \
            oc1 = fmaf(al, f[1], oc1);                          \
            oc2 = fmaf(al, f[2], oc2);                          \
        }
        ACC(0) ACC(1) ACC(2) ACC(3) ACC(4) ACC(5) ACC(6) ACC(7)
#undef ACC

        out[p]            = oc0;
        out[p + NPIX]     = oc1;
        out[p + 2 * NPIX] = oc2;
    }
}

extern "C" void kernel_launch(void* const* d_in, const int* in_sizes, int n_in,
                              void* d_out, int out_size, void* d_ws, size_t ws_size,
                              hipStream_t stream) {
    const float* xy    = (const float*)d_in[0];
    const float* scale = (const float*)d_in[1];
    const float* rot   = (const float*)d_in[2];
    const float* feat  = (const float*)d_in[3];
    float* out = (float*)d_out;
    GParam* gp = (GParam*)d_ws;  // 2048 * 32B = 64 KB scratch

    prep_kernel<<<(N_GAUSS + 255) / 256, 256, 0, stream>>>(xy, scale, rot, gp);
    splat_kernel<<<NPIX / PIXB, NTHREADS, 0, stream>>>(gp, feat, out);
}

// Round 4
// 30.540 us; speedup vs baseline: 11.2135x; 4.7102x over previous
//
#include <hip/hip_runtime.h>
#include <math.h>

#define N_GAUSS 2048
#define IMG_H 256
#define IMG_W 256
#define NPIX (IMG_H * IMG_W)
#define EPS 1e-4f

#define TILE 8
#define TILES_X (IMG_W / TILE)          // 32
#define NTILES (TILES_X * (IMG_H / TILE))  // 1024
#define CSTRIDE N_GAUSS                 // worst-case candidate list per tile
// Half-diagonal of the 8x8 pixel-center extent: 3.5*sqrt(2)/256 = 0.01933495
#define D_HALF 0.019336f                // strictly above the exact value

// ws layout
#define WS_GP_OFF     0
#define WS_COUNT_OFF  (N_GAUSS * 32)                       // 64 KB
#define WS_CAND_OFF   (WS_COUNT_OFF + 4096)                // +4 KB
#define WS_NEEDED     (WS_CAND_OFF + (size_t)NTILES * CSTRIDE * 2)

// Per-gaussian parameters, 32B (two float4s).
struct GParam {
    float x, y;    // center
    float c, s;    // cos(rot), sin(rot) -- fp32-rounded from double trig
    float sx, sy;  // inverse std-devs
    float pad0, pad1;
};

__global__ void prep_kernel(const float* __restrict__ xy,
                            const float* __restrict__ scale,
                            const float* __restrict__ rot,
                            GParam* __restrict__ gp) {
    int g = blockIdx.x * blockDim.x + threadIdx.x;
    if (g >= N_GAUSS) return;
    GParam o;
    o.x  = xy[2 * g + 0];
    o.y  = xy[2 * g + 1];
    o.sx = scale[2 * g + 0];
    o.sy = scale[2 * g + 1];
    double r = (double)rot[g];
    o.c = (float)cos(r);   // correctly-rounded fp32 trig (numpy-matching)
    o.s = (float)sin(r);
    o.pad0 = 0.f; o.pad1 = 0.f;
    gp[g] = o;
}

// Strict-< sorted-insert ladder; lowest index wins ties (top_k stable order).
#define LADDER(T, G)                                                     \
    if ((T) < v7) {                                                      \
        const bool c0 = (T) < v0, c1 = (T) < v1, c2 = (T) < v2;          \
        const bool c3 = (T) < v3, c4 = (T) < v4, c5 = (T) < v5;          \
        const bool c6 = (T) < v6;                                        \
        v7 = c6 ? v6 : (T);            i7 = c6 ? i6 : (G);               \
        v6 = c6 ? (c5 ? v5 : (T)) : v6; i6 = c6 ? (c5 ? i5 : (G)) : i6;  \
        v5 = c5 ? (c4 ? v4 : (T)) : v5; i5 = c5 ? (c4 ? i4 : (G)) : i5;  \
        v4 = c4 ? (c3 ? v3 : (T)) : v4; i4 = c4 ? (c3 ? i3 : (G)) : i4;  \
        v3 = c3 ? (c2 ? v2 : (T)) : v3; i3 = c3 ? (c2 ? i2 : (G)) : i3;  \
        v2 = c2 ? (c1 ? v1 : (T)) : v2; i2 = c2 ? (c1 ? i1 : (G)) : i2;  \
        v1 = c1 ? (c0 ? v0 : (T)) : v1; i1 = c1 ? (c0 ? i0 : (G)) : i1;  \
        v0 = c0 ? (T) : v0;            i0 = c0 ? (G) : i0;               \
    }

// values-only ladder (screening)
#define VLADDER(T)                                                       \
    if ((T) < v7) {                                                      \
        const bool c0 = (T) < v0, c1 = (T) < v1, c2 = (T) < v2;          \
        const bool c3 = (T) < v3, c4 = (T) < v4, c5 = (T) < v5;          \
        const bool c6 = (T) < v6;                                        \
        v7 = c6 ? v6 : (T);                                              \
        v6 = c6 ? (c5 ? v5 : (T)) : v6;                                  \
        v5 = c5 ? (c4 ? v4 : (T)) : v5;                                  \
        v4 = c4 ? (c3 ? v3 : (T)) : v4;                                  \
        v3 = c3 ? (c2 ? v2 : (T)) : v3;                                  \
        v2 = c2 ? (c1 ? v1 : (T)) : v2;                                  \
        v1 = c1 ? (c0 ? v0 : (T)) : v1;                                  \
        v0 = c0 ? (T) : v0;                                              \
    }

// Per-tile conservative culling. Keeps a provable superset of every
// pixel-in-tile's exact top-8, written in ascending gaussian-index order.
__launch_bounds__(256)
__global__ void cull_kernel(const GParam* __restrict__ gp,
                            unsigned* __restrict__ counts,
                            unsigned short* __restrict__ cands) {
    __shared__ float rlo[N_GAUSS];      // 8 KB: r(center) - m  per gaussian
    __shared__ float lists[256][9];     // 9 KB: padded sorted-8 lists

    const int tid  = threadIdx.x;
    const int tile = blockIdx.x;
    const float cx = (float)((tile & (TILES_X - 1)) * TILE + 4) * (1.0f / IMG_W);
    const float cy = (float)((tile / TILES_X) * TILE + 4) * (1.0f / IMG_H);

    float v0 = INFINITY, v1 = INFINITY, v2 = INFINITY, v3 = INFINITY;
    float v4 = INFINITY, v5 = INFINITY, v6 = INFINITY, v7 = INFINITY;

    for (int r = 0; r < N_GAUSS / 256; ++r) {
        int g = r * 256 + tid;
        GParam q = gp[g];
        float dx = cx - q.x;
        float dy = cy - q.y;
        float lx = dx * q.c + dy * q.s;
        float ly = dy * q.c - dx * q.s;
        float a  = lx * q.sx;
        float b  = ly * q.sy;
        float rr = sqrtf(a * a + b * b);
        float m  = fmaxf(q.sx, q.sy) * D_HALF;
        rlo[g]   = rr - m;
        float rp = rr + m;
        VLADDER(rp)
    }
    lists[tid][0] = v0; lists[tid][1] = v1; lists[tid][2] = v2; lists[tid][3] = v3;
    lists[tid][4] = v4; lists[tid][5] = v5; lists[tid][6] = v6; lists[tid][7] = v7;
    lists[tid][8] = INFINITY;
    __syncthreads();

    // Exact tree-merge for the global 8th-smallest of (r + m).
    for (int stride = 128; stride >= 1; stride >>= 1) {
        if (tid < stride) {
            float outv[8];
            int ia = 0, ib = 0;
#pragma unroll
            for (int k = 0; k < 8; ++k) {
                float av = lists[tid][ia];           // row padded with INF
                float bv = lists[tid + stride][ib];
                bool ta = av <= bv;
                outv[k] = ta ? av : bv;
                ia += ta ? 1 : 0;
                ib += ta ? 0 : 1;
            }
#pragma unroll
            for (int k = 0; k < 8; ++k) lists[tid][k] = outv[k];
        }
        __syncthreads();
    }
    float cut = lists[0][7];
    cut = cut + 0.01f + 1e-4f * cut;   // >> all float-vs-real error budgets

    // Wave-0 ordered stream compaction (ascending gaussian index).
    if (tid < 64) {
        unsigned short* cl = cands + (size_t)tile * CSTRIDE;
        unsigned base = 0;
        for (int s2 = 0; s2 < N_GAUSS / 64; ++s2) {
            int g = s2 * 64 + tid;
            bool keep = rlo[g] <= cut;
            unsigned long long mask = __ballot(keep);
            unsigned pos = (unsigned)__popcll(mask & ((1ull << tid) - 1ull));
            if (keep) cl[base + pos] = (unsigned short)g;
            base += (unsigned)__popcll(mask);
        }
        if (tid == 0) counts[tile] = base;
    }
}

// Per-tile exact selection over the culled candidate list.
// 4 waves split the (ascending) list; LDS merge preserves global order.
__launch_bounds__(256)
__global__ void splat2_kernel(const GParam* __restrict__ gp,
                              const float* __restrict__ feat,
                              const unsigned* __restrict__ counts,
                              const unsigned short* __restrict__ cands,
                              float* __restrict__ out) {
    __shared__ float4 qa[256];                    // x,y,c,s
    __shared__ float2 qb[256];                    // sx,sy
    __shared__ unsigned short qi[256];
    __shared__ float          lt[4][8][64];       // 8 KB
    __shared__ unsigned short li[4][8][64];       // 4 KB

    const int tid  = threadIdx.x;
    const int lane = tid & 63;
    const int w    = tid >> 6;
    const int tile = blockIdx.x;
    const int pxi  = (tile & (TILES_X - 1)) * TILE + (lane & 7);
    const int pyi  = (tile / TILES_X) * TILE + (lane >> 3);
    const int p    = pyi * IMG_W + pxi;
    const float px = (pxi + 0.5f) * (1.0f / IMG_W);
    const float py = (pyi + 0.5f) * (1.0f / IMG_H);

    const int L  = (int)counts[tile];
    const int L4 = (L + 3) >> 2;
    int start = w * L4; if (start > L) start = L;
    int end   = start + L4; if (end > L) end = L;

    const unsigned short* cl = cands + (size_t)tile * CSTRIDE;

    float v0 = INFINITY, v1 = INFINITY, v2 = INFINITY, v3 = INFINITY;
    float v4 = INFINITY, v5 = INFINITY, v6 = INFINITY, v7 = INFINITY;
    int   i0 = 0, i1 = 0, i2 = 0, i3 = 0, i4 = 0, i5 = 0, i6 = 0, i7 = 0;

    for (int base = 0; base < L; base += 256) {
        int t = base + tid;
        if (t < L) {
            int g = cl[t];
            const float4* g4 = (const float4*)(gp + g);
            float4 a4 = g4[0];
            float4 b4 = g4[1];
            qa[tid] = a4;
            qb[tid] = make_float2(b4.x, b4.y);
            qi[tid] = (unsigned short)g;
        }
        __syncthreads();
        int jlo = start > base ? start : base;
        int lim = base + 256; if (lim > end) lim = end;
        for (int j = jlo; j < lim; ++j) {
            int k = j - base;
            float4 a4 = qa[k];
            float2 b2 = qb[k];
            int g = (int)qi[k];
            // Bit-exact reference arithmetic (one rounding per op, no fma):
            float dx = __fsub_rn(px, a4.x);
            float dy = __fsub_rn(py, a4.y);
            float lx = __fadd_rn(__fmul_rn(dx, a4.z), __fmul_rn(dy, a4.w));
            float ly = __fadd_rn(__fmul_rn(-dx, a4.w), __fmul_rn(dy, a4.z));
            float aa = __fmul_rn(lx, b2.x);
            float bb = __fmul_rn(ly, b2.y);
            float t2 = __fadd_rn(__fmul_rn(aa, aa), __fmul_rn(bb, bb));
            LADDER(t2, g)
        }
        __syncthreads();
    }

    lt[w][0][lane] = v0; li[w][0][lane] = (unsigned short)i0;
    lt[w][1][lane] = v1; li[w][1][lane] = (unsigned short)i1;
    lt[w][2][lane] = v2; li[w][2][lane] = (unsigned short)i2;
    lt[w][3][lane] = v3; li[w][3][lane] = (unsigned short)i3;
    lt[w][4][lane] = v4; li[w][4][lane] = (unsigned short)i4;
    lt[w][5][lane] = v5; li[w][5][lane] = (unsigned short)i5;
    lt[w][6][lane] = v6; li[w][6][lane] = (unsigned short)i6;
    lt[w][7][lane] = v7; li[w][7][lane] = (unsigned short)i7;
    __syncthreads();

    if (w == 0) {
        v0 = INFINITY; v1 = INFINITY; v2 = INFINITY; v3 = INFINITY;
        v4 = INFINITY; v5 = INFINITY; v6 = INFINITY; v7 = INFINITY;
        i0 = 0; i1 = 0; i2 = 0; i3 = 0; i4 = 0; i5 = 0; i6 = 0; i7 = 0;
        for (int c = 0; c < 4; ++c) {
#pragma unroll
            for (int k = 0; k < 8; ++k) {
                float t2 = lt[c][k][lane];
                int   g  = (int)li[c][k][lane];
                LADDER(t2, g)
            }
        }
        float w0 = expf(-0.5f * v0), w1 = expf(-0.5f * v1);
        float w2 = expf(-0.5f * v2), w3 = expf(-0.5f * v3);
        float w4 = expf(-0.5f * v4), w5 = expf(-0.5f * v5);
        float w6 = expf(-0.5f * v6), w7 = expf(-0.5f * v7);
        float sum = w0 + w1 + w2 + w3 + w4 + w5 + w6 + w7;
        float inv = 1.0f / (sum + EPS);

        float oc0 = 0.f, oc1 = 0.f, oc2 = 0.f;
#define ACC(K)                                                  \
        {                                                       \
            float al = w##K * inv;                              \
            const float* f = feat + 3 * i##K;                   \
            oc0 = fmaf(al, f[0], oc0);                          \
            oc1 = fmaf(al, f[1], oc1);                          \
            oc2 = fmaf(al, f[2], oc2);                          \
        }
        ACC(0) ACC(1) ACC(2) ACC(3) ACC(4) ACC(5) ACC(6) ACC(7)
#undef ACC

        out[p]            = oc0;
        out[p + NPIX]     = oc1;
        out[p + 2 * NPIX] = oc2;
    }
}

// ---------- Fallback (proven R3 path) if ws is too small ----------
#define FSPLIT 8
#define FCHUNK (N_GAUSS / FSPLIT)
#define FPIXB 128
#define FNTH (FPIXB * FSPLIT)

__launch_bounds__(FNTH)
__global__ void splat_fb_kernel(const GParam* __restrict__ gp,
                                const float* __restrict__ feat,
                                float* __restrict__ out) {
    __shared__ float          lt[FSPLIT][8][FPIXB];
    __shared__ unsigned short li[FSPLIT][8][FPIXB];

    const int tid   = threadIdx.x;
    const int pix   = tid & (FPIXB - 1);
    const int chunk = tid >> 7;
    const int p     = blockIdx.x * FPIXB + pix;
    const float px = ((p & (IMG_W - 1)) + 0.5f) * (1.0f / IMG_W);
    const float py = ((p >> 8) + 0.5f) * (1.0f / IMG_H);

    float v0 = INFINITY, v1 = INFINITY, v2 = INFINITY, v3 = INFINITY;
    float v4 = INFINITY, v5 = INFINITY, v6 = INFINITY, v7 = INFINITY;
    int   i0 = 0, i1 = 0, i2 = 0, i3 = 0, i4 = 0, i5 = 0, i6 = 0, i7 = 0;

    const int gbase = chunk * FCHUNK;
    const GParam* gptr = gp + gbase;
#define FPROC(CF, G)                                                      \
    {                                                                     \
        float dx = __fsub_rn(px, (CF).x);                                 \
        float dy = __fsub_rn(py, (CF).y);                                 \
        float lx = __fadd_rn(__fmul_rn(dx, (CF).c), __fmul_rn(dy, (CF).s)); \
        float ly = __fadd_rn(__fmul_rn(-dx, (CF).s), __fmul_rn(dy, (CF).c)); \
        float a  = __fmul_rn(lx, (CF).sx);                                \
        float b  = __fmul_rn(ly, (CF).sy);                                \
        float t  = __fadd_rn(__fmul_rn(a, a), __fmul_rn(b, b));           \
        LADDER(t, (G))                                                    \
    }
    GParam c0r = gptr[0];
    GParam c1r = gptr[1];
    for (int j = 0; j < FCHUNK - 2; j += 2) {
        GParam n0 = gptr[j + 2];
        GParam n1 = gptr[j + 3];
        FPROC(c0r, gbase + j)
        FPROC(c1r, gbase + j + 1)
        c0r = n0; c1r = n1;
    }
    FPROC(c0r, gbase + FCHUNK - 2)
    FPROC(c1r, gbase + FCHUNK - 1)
#undef FPROC

    lt[chunk][0][pix] = v0; li[chunk][0][pix] = (unsigned short)i0;
    lt[chunk][1][pix] = v1; li[chunk][1][pix] = (unsigned short)i1;
    lt[chunk][2][pix] = v2; li[chunk][2][pix] = (unsigned short)i2;
    lt[chunk][3][pix] = v3; li[chunk][3][pix] = (unsigned short)i3;
    lt[chunk][4][pix] = v4; li[chunk][4][pix] = (unsigned short)i4;
    lt[chunk][5][pix] = v5; li[chunk][5][pix] = (unsigned short)i5;
    lt[chunk][6][pix] = v6; li[chunk][6][pix] = (unsigned short)i6;
    lt[chunk][7][pix] = v7; li[chunk][7][pix] = (unsigned short)i7;
    __syncthreads();

    if (chunk == 0) {
        v0 = INFINITY; v1 = INFINITY; v2 = INFINITY; v3 = INFINITY;
        v4 = INFINITY; v5 = INFINITY; v6 = INFINITY; v7 = INFINITY;
        i0 = 0; i1 = 0; i2 = 0; i3 = 0; i4 = 0; i5 = 0; i6 = 0; i7 = 0;
        for (int c = 0; c < FSPLIT; ++c) {
#pragma unroll
            for (int k = 0; k < 8; ++k) {
                float t = lt[c][k][pix];
                int   g = (int)li[c][k][pix];
                LADDER(t, g)
            }
        }
        float w0 = expf(-0.5f * v0), w1 = expf(-0.5f * v1);
        float w2 = expf(-0.5f * v2), w3 = expf(-0.5f * v3);
        float w4 = expf(-0.5f * v4), w5 = expf(-0.5f * v5);
        float w6 = expf(-0.5f * v6), w7 = expf(-0.5f * v7);
        float sum = w0 + w1 + w2 + w3 + w4 + w5 + w6 + w7;
        float inv = 1.0f / (sum + EPS);
        float oc0 = 0.f, oc1 = 0.f, oc2 = 0.f;
#define ACC(K)                                                  \
        {                                                       \
            float al = w##K * inv;                              \
            const float* f = feat + 3 * i##K;                   \
            oc0 = fmaf(al, f[0], oc0);                          \
            oc1 = fmaf(al, f[1], oc1);                          \
            oc2 = fmaf(al, f[2], oc2);                          \
        }
        ACC(0) ACC(1) ACC(2) ACC(3) ACC(4) ACC(5) ACC(6) ACC(7)
#undef ACC
        out[p]            = oc0;
        out[p + NPIX]     = oc1;
        out[p + 2 * NPIX] = oc2;
    }
}

extern "C" void kernel_launch(void* const* d_in, const int* in_sizes, int n_in,
                              void* d_out, int out_size, void* d_ws, size_t ws_size,
                              hipStream_t stream) {
    const float* xy    = (const float*)d_in[0];
    const float* scale = (const float*)d_in[1];
    const float* rot   = (const float*)d_in[2];
    const float* feat  = (const float*)d_in[3];
    float* out = (float*)d_out;

    char* ws = (char*)d_ws;
    GParam* gp = (GParam*)(ws + WS_GP_OFF);

    prep_kernel<<<(N_GAUSS + 255) / 256, 256, 0, stream>>>(xy, scale, rot, gp);

    if (ws_size >= WS_NEEDED) {
        unsigned*       counts = (unsigned*)(ws + WS_COUNT_OFF);
        unsigned short* cands  = (unsigned short*)(ws + WS_CAND_OFF);
        cull_kernel<<<NTILES, 256, 0, stream>>>(gp, counts, cands);
        splat2_kernel<<<NTILES, 256, 0, stream>>>(gp, feat, counts, cands, out);
    } else {
        splat_fb_kernel<<<NPIX / FPIXB, FNTH, 0, stream>>>(gp, feat, out);
    }
}

// Round 5
// 29.187 us; speedup vs baseline: 11.7333x; 1.0464x over previous
//
#include <hip/hip_runtime.h>
#include <math.h>

#define N_GAUSS 2048
#define IMG_H 256
#define IMG_W 256
#define NPIX (IMG_H * IMG_W)
#define EPS 1e-4f

#define TILE 8
#define TILES_X (IMG_W / TILE)             // 32
#define NTILES (TILES_X * (IMG_H / TILE))  // 1024
// Half-diagonal of the 8x8 pixel-center extent: 3.5*sqrt(2)/256 = 0.01933495
#define D_HALF 0.019336f                   // strictly above the exact value

// Per-gaussian parameters, 32B (two float4s).
struct GParam {
    float x, y;    // center
    float c, s;    // cos(rot), sin(rot) -- fp32-rounded from double trig
    float sx, sy;  // inverse std-devs
    float pad0, pad1;
};

__global__ void prep_kernel(const float* __restrict__ xy,
                            const float* __restrict__ scale,
                            const float* __restrict__ rot,
                            GParam* __restrict__ gp) {
    int g = blockIdx.x * blockDim.x + threadIdx.x;
    if (g >= N_GAUSS) return;
    GParam o;
    o.x  = xy[2 * g + 0];
    o.y  = xy[2 * g + 1];
    o.sx = scale[2 * g + 0];
    o.sy = scale[2 * g + 1];
    double r = (double)rot[g];
    o.c = (float)cos(r);   // correctly-rounded fp32 trig (numpy-matching)
    o.s = (float)sin(r);
    o.pad0 = 0.f; o.pad1 = 0.f;
    gp[g] = o;
}

// Strict-< sorted-insert ladder; lowest index wins ties (top_k stable order).
#define LADDER(T, G)                                                     \
    if ((T) < v7) {                                                      \
        const bool c0 = (T) < v0, c1 = (T) < v1, c2 = (T) < v2;          \
        const bool c3 = (T) < v3, c4 = (T) < v4, c5 = (T) < v5;          \
        const bool c6 = (T) < v6;                                        \
        v7 = c6 ? v6 : (T);            i7 = c6 ? i6 : (G);               \
        v6 = c6 ? (c5 ? v5 : (T)) : v6; i6 = c6 ? (c5 ? i5 : (G)) : i6;  \
        v5 = c5 ? (c4 ? v4 : (T)) : v5; i5 = c5 ? (c4 ? i4 : (G)) : i5;  \
        v4 = c4 ? (c3 ? v3 : (T)) : v4; i4 = c4 ? (c3 ? i3 : (G)) : i4;  \
        v3 = c3 ? (c2 ? v2 : (T)) : v3; i3 = c3 ? (c2 ? i2 : (G)) : i3;  \
        v2 = c2 ? (c1 ? v1 : (T)) : v2; i2 = c2 ? (c1 ? i1 : (G)) : i2;  \
        v1 = c1 ? (c0 ? v0 : (T)) : v1; i1 = c1 ? (c0 ? i0 : (G)) : i1;  \
        v0 = c0 ? (T) : v0;            i0 = c0 ? (G) : i0;               \
    }

// values-only ladder (screening)
#define VLADDER(T)                                                       \
    if ((T) < v7) {                                                      \
        const bool c0 = (T) < v0, c1 = (T) < v1, c2 = (T) < v2;          \
        const bool c3 = (T) < v3, c4 = (T) < v4, c5 = (T) < v5;          \
        const bool c6 = (T) < v6;                                        \
        v7 = c6 ? v6 : (T);                                              \
        v6 = c6 ? (c5 ? v5 : (T)) : v6;                                  \
        v5 = c5 ? (c4 ? v4 : (T)) : v5;                                  \
        v4 = c4 ? (c3 ? v3 : (T)) : v4;                                  \
        v3 = c3 ? (c2 ? v2 : (T)) : v3;                                  \
        v2 = c2 ? (c1 ? v1 : (T)) : v2;                                  \
        v1 = c1 ? (c0 ? v0 : (T)) : v1;                                  \
        v0 = c0 ? (T) : v0;                                              \
    }

// Fused per-tile kernel: conservative cull (exact tile-level top-8 bound,
// ordered compaction to LDS) + bit-exact per-pixel top-8 + blend.
__launch_bounds__(256)
__global__ void fused_kernel(const GParam* __restrict__ gp,
                             const float* __restrict__ feat,
                             float* __restrict__ out) {
    __shared__ float rlo[N_GAUSS];            // 8 KB: r(center)-m per gaussian
    __shared__ float lists[256][9];           // 9 KB: padded sorted-8 lists
    __shared__ unsigned short qidx[N_GAUSS];  // 4 KB: compacted candidates
    __shared__ unsigned qcount;
    __shared__ float4 qa[256];                // staging: x,y,c,s
    __shared__ float2 qb[256];                // staging: sx,sy
    __shared__ unsigned short qi[256];
    __shared__ float          lt[4][8][64];   // 8 KB merge buf
    __shared__ unsigned short li[4][8][64];   // 4 KB

    const int tid  = threadIdx.x;
    const int lane = tid & 63;
    const int w    = tid >> 6;
    const int tile = blockIdx.x;

    // ---------------- Phase A: screen all gaussians vs tile center ---------
    const float cx = (float)((tile & (TILES_X - 1)) * TILE + 4) * (1.0f / IMG_W);
    const float cy = (float)((tile / TILES_X) * TILE + 4) * (1.0f / IMG_H);
    {
        float v0 = INFINITY, v1 = INFINITY, v2 = INFINITY, v3 = INFINITY;
        float v4 = INFINITY, v5 = INFINITY, v6 = INFINITY, v7 = INFINITY;
        for (int r = 0; r < N_GAUSS / 256; ++r) {
            int g = r * 256 + tid;
            GParam q = gp[g];
            float dx = cx - q.x;
            float dy = cy - q.y;
            float lx = dx * q.c + dy * q.s;
            float ly = dy * q.c - dx * q.s;
            float a  = lx * q.sx;
            float b  = ly * q.sy;
            float rr = sqrtf(a * a + b * b);
            float m  = fmaxf(q.sx, q.sy) * D_HALF;
            rlo[g]   = rr - m;
            float rp = rr + m;
            VLADDER(rp)
        }
        lists[tid][0] = v0; lists[tid][1] = v1; lists[tid][2] = v2; lists[tid][3] = v3;
        lists[tid][4] = v4; lists[tid][5] = v5; lists[tid][6] = v6; lists[tid][7] = v7;
        lists[tid][8] = INFINITY;
    }
    __syncthreads();

    // ---------------- Phase B: exact tree-merge -> global 8th-smallest -----
    for (int stride = 128; stride >= 1; stride >>= 1) {
        if (tid < stride) {
            float outv[8];
            int ia = 0, ib = 0;
#pragma unroll
            for (int k = 0; k < 8; ++k) {
                float av = lists[tid][ia];            // rows padded with INF
                float bv = lists[tid + stride][ib];
                bool ta = av <= bv;
                outv[k] = ta ? av : bv;
                ia += ta ? 1 : 0;
                ib += ta ? 0 : 1;
            }
#pragma unroll
            for (int k = 0; k < 8; ++k) lists[tid][k] = outv[k];
        }
        __syncthreads();
    }
    float cut = lists[0][7];
    cut = cut + 0.01f + 1e-4f * cut;   // slack >> all float-vs-real error budgets

    // ---------------- Phase C: ordered ballot compaction (wave 0) ----------
    if (tid < 64) {
        unsigned base = 0;
        for (int s2 = 0; s2 < N_GAUSS / 64; ++s2) {
            int g = s2 * 64 + tid;
            bool keep = rlo[g] <= cut;
            unsigned long long mask = __ballot(keep);
            unsigned pos = (unsigned)__popcll(mask & ((1ull << tid) - 1ull));
            if (keep) qidx[base + pos] = (unsigned short)g;
            base += (unsigned)__popcll(mask);
        }
        if (tid == 0) qcount = base;
    }
    __syncthreads();

    // ---------------- Phase D: bit-exact top-8 over candidates -------------
    const int pxi = (tile & (TILES_X - 1)) * TILE + (lane & 7);
    const int pyi = (tile / TILES_X) * TILE + (lane >> 3);
    const int p   = pyi * IMG_W + pxi;
    const float px = (pxi + 0.5f) * (1.0f / IMG_W);
    const float py = (pyi + 0.5f) * (1.0f / IMG_H);

    const int L  = (int)qcount;
    const int L4 = (L + 3) >> 2;
    int start = w * L4; if (start > L) start = L;
    int end   = start + L4; if (end > L) end = L;

    float v0 = INFINITY, v1 = INFINITY, v2 = INFINITY, v3 = INFINITY;
    float v4 = INFINITY, v5 = INFINITY, v6 = INFINITY, v7 = INFINITY;
    int   i0 = 0, i1 = 0, i2 = 0, i3 = 0, i4 = 0, i5 = 0, i6 = 0, i7 = 0;

    for (int base = 0; base < L; base += 256) {
        int t = base + tid;
        if (t < L) {
            int g = qidx[t];
            const float4* g4 = (const float4*)(gp + g);
            float4 a4 = g4[0];
            float4 b4 = g4[1];
            qa[tid] = a4;
            qb[tid] = make_float2(b4.x, b4.y);
            qi[tid] = (unsigned short)g;
        }
        __syncthreads();
        int jlo = start > base ? start : base;
        int lim = base + 256; if (lim > end) lim = end;
        for (int j = jlo; j < lim; ++j) {
            int k = j - base;
            float4 a4 = qa[k];
            float2 b2 = qb[k];
            int g = (int)qi[k];
            // Bit-exact reference arithmetic (one rounding per op, no fma):
            float dx = __fsub_rn(px, a4.x);
            float dy = __fsub_rn(py, a4.y);
            float lx = __fadd_rn(__fmul_rn(dx, a4.z), __fmul_rn(dy, a4.w));
            float ly = __fadd_rn(__fmul_rn(-dx, a4.w), __fmul_rn(dy, a4.z));
            float aa = __fmul_rn(lx, b2.x);
            float bb = __fmul_rn(ly, b2.y);
            float t2 = __fadd_rn(__fmul_rn(aa, aa), __fmul_rn(bb, bb));
            LADDER(t2, g)
        }
        __syncthreads();
    }

    lt[w][0][lane] = v0; li[w][0][lane] = (unsigned short)i0;
    lt[w][1][lane] = v1; li[w][1][lane] = (unsigned short)i1;
    lt[w][2][lane] = v2; li[w][2][lane] = (unsigned short)i2;
    lt[w][3][lane] = v3; li[w][3][lane] = (unsigned short)i3;
    lt[w][4][lane] = v4; li[w][4][lane] = (unsigned short)i4;
    lt[w][5][lane] = v5; li[w][5][lane] = (unsigned short)i5;
    lt[w][6][lane] = v6; li[w][6][lane] = (unsigned short)i6;
    lt[w][7][lane] = v7; li[w][7][lane] = (unsigned short)i7;
    __syncthreads();

    if (w == 0) {
        v0 = INFINITY; v1 = INFINITY; v2 = INFINITY; v3 = INFINITY;
        v4 = INFINITY; v5 = INFINITY; v6 = INFINITY; v7 = INFINITY;
        i0 = 0; i1 = 0; i2 = 0; i3 = 0; i4 = 0; i5 = 0; i6 = 0; i7 = 0;
        // Ascending wave order == ascending gaussian-index order -> identical
        // selection/ordering to the single-stream ladder.
        for (int c = 0; c < 4; ++c) {
#pragma unroll
            for (int k = 0; k < 8; ++k) {
                float t2 = lt[c][k][lane];
                int   g  = (int)li[c][k][lane];
                LADDER(t2, g)
            }
        }
        float w0 = expf(-0.5f * v0), w1 = expf(-0.5f * v1);
        float w2 = expf(-0.5f * v2), w3 = expf(-0.5f * v3);
        float w4 = expf(-0.5f * v4), w5 = expf(-0.5f * v5);
        float w6 = expf(-0.5f * v6), w7 = expf(-0.5f * v7);
        float sum = w0 + w1 + w2 + w3 + w4 + w5 + w6 + w7;
        float inv = 1.0f / (sum + EPS);

        float oc0 = 0.f, oc1 = 0.f, oc2 = 0.f;
#define ACC(K)                                                  \
        {                                                       \
            float al = w##K * inv;                              \
            const float* f = feat + 3 * i##K;                   \
            oc0 = fmaf(al, f[0], oc0);                          \
            oc1 = fmaf(al, f[1], oc1);                          \
            oc2 = fmaf(al, f[2], oc2);                          \
        }
        ACC(0) ACC(1) ACC(2) ACC(3) ACC(4) ACC(5) ACC(6) ACC(7)
#undef ACC

        out[p]            = oc0;
        out[p + NPIX]     = oc1;
        out[p + 2 * NPIX] = oc2;
    }
}

extern "C" void kernel_launch(void* const* d_in, const int* in_sizes, int n_in,
                              void* d_out, int out_size, void* d_ws, size_t ws_size,
                              hipStream_t stream) {
    const float* xy    = (const float*)d_in[0];
    const float* scale = (const float*)d_in[1];
    const float* rot   = (const float*)d_in[2];
    const float* feat  = (const float*)d_in[3];
    float* out = (float*)d_out;
    GParam* gp = (GParam*)d_ws;  // 2048 * 32B = 64 KB scratch

    prep_kernel<<<(N_GAUSS + 255) / 256, 256, 0, stream>>>(xy, scale, rot, gp);
    fused_kernel<<<NTILES, 256, 0, stream>>>(gp, feat, out);
}

// Round 6
// 28.788 us; speedup vs baseline: 11.8960x; 1.0139x over previous
//
#include <hip/hip_runtime.h>
#include <math.h>

#define N_GAUSS 2048
#define IMG_H 256
#define IMG_W 256
#define NPIX (IMG_H * IMG_W)
#define EPS 1e-4f

#define TILE 8
#define TILES_X (IMG_W / TILE)             // 32
#define NTILES (TILES_X * (IMG_H / TILE))  // 1024
#define SEG 512                            // gaussians per wave-segment
// Half-diagonal of the 8x8 pixel-center extent: 3.5*sqrt(2)/256 = 0.01933495
#define D_HALF 0.019336f                   // strictly above the exact value

// Per-gaussian parameters, 32B (two float4s).
struct GParam {
    float x, y;    // center
    float c, s;    // cos(rot), sin(rot) -- fp32-rounded from double trig
    float sx, sy;  // inverse std-devs
    float pad0, pad1;
};

__global__ void prep_kernel(const float* __restrict__ xy,
                            const float* __restrict__ scale,
                            const float* __restrict__ rot,
                            GParam* __restrict__ gp) {
    int g = blockIdx.x * blockDim.x + threadIdx.x;
    if (g >= N_GAUSS) return;
    GParam o;
    o.x  = xy[2 * g + 0];
    o.y  = xy[2 * g + 1];
    o.sx = scale[2 * g + 0];
    o.sy = scale[2 * g + 1];
    double r = (double)rot[g];
    o.c = (float)cos(r);   // correctly-rounded fp32 trig (numpy-matching)
    o.s = (float)sin(r);
    o.pad0 = 0.f; o.pad1 = 0.f;
    gp[g] = o;
}

// Strict-< sorted-insert ladder; lowest index wins ties (top_k stable order).
#define LADDER(T, G)                                                     \
    if ((T) < v7) {                                                      \
        const bool c0 = (T) < v0, c1 = (T) < v1, c2 = (T) < v2;          \
        const bool c3 = (T) < v3, c4 = (T) < v4, c5 = (T) < v5;          \
        const bool c6 = (T) < v6;                                        \
        v7 = c6 ? v6 : (T);            i7 = c6 ? i6 : (G);               \
        v6 = c6 ? (c5 ? v5 : (T)) : v6; i6 = c6 ? (c5 ? i5 : (G)) : i6;  \
        v5 = c5 ? (c4 ? v4 : (T)) : v5; i5 = c5 ? (c4 ? i4 : (G)) : i5;  \
        v4 = c4 ? (c3 ? v3 : (T)) : v4; i4 = c4 ? (c3 ? i3 : (G)) : i4;  \
        v3 = c3 ? (c2 ? v2 : (T)) : v3; i3 = c3 ? (c2 ? i2 : (G)) : i3;  \
        v2 = c2 ? (c1 ? v1 : (T)) : v2; i2 = c2 ? (c1 ? i1 : (G)) : i2;  \
        v1 = c1 ? (c0 ? v0 : (T)) : v1; i1 = c1 ? (c0 ? i0 : (G)) : i1;  \
        v0 = c0 ? (T) : v0;            i0 = c0 ? (G) : i0;               \
    }

// values-only ladder (screening)
#define VLADDER(T)                                                       \
    if ((T) < v7) {                                                      \
        const bool c0 = (T) < v0, c1 = (T) < v1, c2 = (T) < v2;          \
        const bool c3 = (T) < v3, c4 = (T) < v4, c5 = (T) < v5;          \
        const bool c6 = (T) < v6;                                        \
        v7 = c6 ? v6 : (T);                                              \
        v6 = c6 ? (c5 ? v5 : (T)) : v6;                                  \
        v5 = c5 ? (c4 ? v4 : (T)) : v5;                                  \
        v4 = c4 ? (c3 ? v3 : (T)) : v4;                                  \
        v3 = c3 ? (c2 ? v2 : (T)) : v3;                                  \
        v2 = c2 ? (c1 ? v1 : (T)) : v2;                                  \
        v1 = c1 ? (c0 ? v0 : (T)) : v1;                                  \
        v0 = c0 ? (T) : v0;                                              \
    }

// Compare-exchange on constant-indexed array elems (registers after unroll).
#define CE(a, i, j)                                   \
    { float lo_ = fminf(a[i], a[j]);                  \
      float hi_ = fmaxf(a[i], a[j]);                  \
      a[i] = lo_; a[j] = hi_; }

// A := sorted 8 smallest of (A ∪ B); A,B ascending. Selection-only (exact).
#define MERGE8(A, B)                                  \
    { float t_[8];                                    \
      t_[0] = fminf(A[0], B[7]); t_[1] = fminf(A[1], B[6]); \
      t_[2] = fminf(A[2], B[5]); t_[3] = fminf(A[3], B[4]); \
      t_[4] = fminf(A[4], B[3]); t_[5] = fminf(A[5], B[2]); \
      t_[6] = fminf(A[6], B[1]); t_[7] = fminf(A[7], B[0]); \
      CE(t_,0,4) CE(t_,1,5) CE(t_,2,6) CE(t_,3,7)     \
      CE(t_,0,2) CE(t_,1,3) CE(t_,4,6) CE(t_,5,7)     \
      CE(t_,0,1) CE(t_,2,3) CE(t_,4,5) CE(t_,6,7)     \
      A[0]=t_[0]; A[1]=t_[1]; A[2]=t_[2]; A[3]=t_[3]; \
      A[4]=t_[4]; A[5]=t_[5]; A[6]=t_[6]; A[7]=t_[7]; }

// Fused per-tile kernel: conservative cull + bit-exact per-pixel top-8 + blend.
__launch_bounds__(256)
__global__ void fused_kernel(const GParam* __restrict__ gp,
                             const float* __restrict__ feat,
                             float* __restrict__ out) {
    __shared__ float rlo[N_GAUSS];            // 8 KB: r(center)-m per gaussian
    __shared__ float wlist[4][8];             // per-wave sorted top-8 of rp
    __shared__ float s_cut;
    __shared__ unsigned short qidx[N_GAUSS];  // 4 KB: per-segment candidates
    __shared__ int qcnt[4];
    __shared__ float          lt[4][8][64];   // 8 KB merge buf
    __shared__ unsigned short li[4][8][64];   // 4 KB

    const int tid  = threadIdx.x;
    const int lane = tid & 63;
    const int w    = tid >> 6;
    const int tile = blockIdx.x;

    // ---------------- Phase A: screen all gaussians vs tile center ---------
    const float cx = (float)((tile & (TILES_X - 1)) * TILE + 4) * (1.0f / IMG_W);
    const float cy = (float)((tile / TILES_X) * TILE + 4) * (1.0f / IMG_H);
    float cur[8];
    {
        float v0 = INFINITY, v1 = INFINITY, v2 = INFINITY, v3 = INFINITY;
        float v4 = INFINITY, v5 = INFINITY, v6 = INFINITY, v7 = INFINITY;
#pragma unroll
        for (int r = 0; r < N_GAUSS / 256; ++r) {
            int g = r * 256 + tid;
            GParam q = gp[g];
            float dx = cx - q.x;
            float dy = cy - q.y;
            float lx = dx * q.c + dy * q.s;
            float ly = dy * q.c - dx * q.s;
            float a  = lx * q.sx;
            float b  = ly * q.sy;
            float rr = sqrtf(a * a + b * b);
            float m  = fmaxf(q.sx, q.sy) * D_HALF;
            rlo[g]   = rr - m;
            float rp = rr + m;
            VLADDER(rp)
        }
        cur[0] = v0; cur[1] = v1; cur[2] = v2; cur[3] = v3;
        cur[4] = v4; cur[5] = v5; cur[6] = v6; cur[7] = v7;
    }

    // ---------------- Phase B: exact top-8 reduce (register bitonic) -------
    // 6-level shuffle butterfly: every lane ends with the wave's exact
    // sorted top-8 of rp. Selection-only ops -> cut is bit-identical to the
    // old tree merge.
#pragma unroll
    for (int m = 1; m < 64; m <<= 1) {
        float oth[8];
#pragma unroll
        for (int k = 0; k < 8; ++k) oth[k] = __shfl_xor(cur[k], m, 64);
        float t_[8];
#pragma unroll
        for (int k = 0; k < 8; ++k) t_[k] = fminf(cur[k], oth[7 - k]);
        CE(t_,0,4) CE(t_,1,5) CE(t_,2,6) CE(t_,3,7)
        CE(t_,0,2) CE(t_,1,3) CE(t_,4,6) CE(t_,5,7)
        CE(t_,0,1) CE(t_,2,3) CE(t_,4,5) CE(t_,6,7)
#pragma unroll
        for (int k = 0; k < 8; ++k) cur[k] = t_[k];
    }
    if (lane == 0) {
#pragma unroll
        for (int k = 0; k < 8; ++k) wlist[w][k] = cur[k];
    }
    __syncthreads();

    if (tid == 0) {
        float A[8], B[8], C2[8], D2[8];
#pragma unroll
        for (int k = 0; k < 8; ++k) {
            A[k]  = wlist[0][k];
            B[k]  = wlist[1][k];
            C2[k] = wlist[2][k];
            D2[k] = wlist[3][k];
        }
        MERGE8(A, B)
        MERGE8(C2, D2)
        MERGE8(A, C2)
        float cut = A[7];
        s_cut = cut + 0.01f + 1e-4f * cut;  // slack >> float-vs-real error budgets
    }
    __syncthreads();
    const float cut = s_cut;

    // ---------------- Phase C: wave-parallel ordered compaction ------------
    // Wave w compacts its own 512-gaussian segment (ascending index order).
    {
        const int segbase = w * SEG;
        unsigned base = 0;
        for (int s2 = 0; s2 < SEG / 64; ++s2) {
            int g = segbase + s2 * 64 + lane;
            bool keep = rlo[g] <= cut;
            unsigned long long mask = __ballot(keep);
            unsigned pos = (unsigned)__popcll(mask & ((1ull << lane) - 1ull));
            if (keep) qidx[segbase + base + pos] = (unsigned short)g;
            base += (unsigned)__popcll(mask);
        }
        if (lane == 0) qcnt[w] = (int)base;
    }
    __syncthreads();

    // ---------------- Phase D: bit-exact top-8 over own segment ------------
    const int pxi = (tile & (TILES_X - 1)) * TILE + (lane & 7);
    const int pyi = (tile / TILES_X) * TILE + (lane >> 3);
    const int p   = pyi * IMG_W + pxi;
    const float px = (pxi + 0.5f) * (1.0f / IMG_W);
    const float py = (pyi + 0.5f) * (1.0f / IMG_H);

    float v0 = INFINITY, v1 = INFINITY, v2 = INFINITY, v3 = INFINITY;
    float v4 = INFINITY, v5 = INFINITY, v6 = INFINITY, v7 = INFINITY;
    int   i0 = 0, i1 = 0, i2 = 0, i3 = 0, i4 = 0, i5 = 0, i6 = 0, i7 = 0;

    {
        const int segbase = w * SEG;
        const int cnt = qcnt[w];
        for (int b = 0; b < cnt; b += 64) {
            int t = b + lane;
            int gg = (t < cnt) ? (int)qidx[segbase + t] : 0;
            const float4* g4 = (const float4*)(gp + gg);
            float4 pa  = g4[0];
            float4 pb4 = g4[1];
            float pbx = pb4.x, pby = pb4.y;
            int lim = cnt - b; if (lim > 64) lim = 64;
            for (int j = 0; j < lim; ++j) {
                // Broadcast candidate j's params from lane j (race-free,
                // register exchange; values bit-identical to a direct load).
                float ax = __shfl(pa.x, j, 64);
                float ay = __shfl(pa.y, j, 64);
                float ac = __shfl(pa.z, j, 64);
                float sn = __shfl(pa.w, j, 64);
                float bx = __shfl(pbx, j, 64);
                float by = __shfl(pby, j, 64);
                int   g  = __shfl(gg,  j, 64);
                // Bit-exact reference arithmetic (one rounding per op, no fma):
                float dx = __fsub_rn(px, ax);
                float dy = __fsub_rn(py, ay);
                float lx = __fadd_rn(__fmul_rn(dx, ac), __fmul_rn(dy, sn));
                float ly = __fadd_rn(__fmul_rn(-dx, sn), __fmul_rn(dy, ac));
                float aa = __fmul_rn(lx, bx);
                float bb = __fmul_rn(ly, by);
                float t2 = __fadd_rn(__fmul_rn(aa, aa), __fmul_rn(bb, bb));
                LADDER(t2, g)
            }
        }
    }

    lt[w][0][lane] = v0; li[w][0][lane] = (unsigned short)i0;
    lt[w][1][lane] = v1; li[w][1][lane] = (unsigned short)i1;
    lt[w][2][lane] = v2; li[w][2][lane] = (unsigned short)i2;
    lt[w][3][lane] = v3; li[w][3][lane] = (unsigned short)i3;
    lt[w][4][lane] = v4; li[w][4][lane] = (unsigned short)i4;
    lt[w][5][lane] = v5; li[w][5][lane] = (unsigned short)i5;
    lt[w][6][lane] = v6; li[w][6][lane] = (unsigned short)i6;
    lt[w][7][lane] = v7; li[w][7][lane] = (unsigned short)i7;
    __syncthreads();

    if (w == 0) {
        v0 = INFINITY; v1 = INFINITY; v2 = INFINITY; v3 = INFINITY;
        v4 = INFINITY; v5 = INFINITY; v6 = INFINITY; v7 = INFINITY;
        i0 = 0; i1 = 0; i2 = 0; i3 = 0; i4 = 0; i5 = 0; i6 = 0; i7 = 0;
        // Ascending wave order == ascending segment == ascending gaussian
        // index -> identical selection/ordering to the single-stream ladder.
        for (int c = 0; c < 4; ++c) {
#pragma unroll
            for (int k = 0; k < 8; ++k) {
                float t2 = lt[c][k][lane];
                int   g  = (int)li[c][k][lane];
                LADDER(t2, g)
            }
        }
        float w0 = expf(-0.5f * v0), w1 = expf(-0.5f * v1);
        float w2 = expf(-0.5f * v2), w3 = expf(-0.5f * v3);
        float w4 = expf(-0.5f * v4), w5 = expf(-0.5f * v5);
        float w6 = expf(-0.5f * v6), w7 = expf(-0.5f * v7);
        float sum = w0 + w1 + w2 + w3 + w4 + w5 + w6 + w7;
        float inv = 1.0f / (sum + EPS);

        float oc0 = 0.f, oc1 = 0.f, oc2 = 0.f;
#define ACC(K)                                                  \
        {                                                       \
            float al = w##K * inv;                              \
            const float* f = feat + 3 * i##K;                   \
            oc0 = fmaf(al, f[0], oc0);                          \
            oc1 = fmaf(al, f[1], oc1);                          \
            oc2 = fmaf(al, f[2], oc2);                          \
        }
        ACC(0) ACC(1) ACC(2) ACC(3) ACC(4) ACC(5) ACC(6) ACC(7)
#undef ACC

        out[p]            = oc0;
        out[p + NPIX]     = oc1;
        out[p + 2 * NPIX] = oc2;
    }
}

extern "C" void kernel_launch(void* const* d_in, const int* in_sizes, int n_in,
                              void* d_out, int out_size, void* d_ws, size_t ws_size,
                              hipStream_t stream) {
    const float* xy    = (const float*)d_in[0];
    const float* scale = (const float*)d_in[1];
    const float* rot   = (const float*)d_in[2];
    const float* feat  = (const float*)d_in[3];
    float* out = (float*)d_out;
    GParam* gp = (GParam*)d_ws;  // 2048 * 32B = 64 KB scratch

    prep_kernel<<<32, 64, 0, stream>>>(xy, scale, rot, gp);
    fused_kernel<<<NTILES, 256, 0, stream>>>(gp, feat, out);
}

// Round 7
// 24.805 us; speedup vs baseline: 13.8062x; 1.1606x over previous
//
#include <hip/hip_runtime.h>
#include <math.h>

#define N_GAUSS 2048
#define IMG_H 256
#define IMG_W 256
#define NPIX (IMG_H * IMG_W)
#define EPS 1e-4f

#define TILE 8
#define TILES_X (IMG_W / TILE)             // 32
#define NTILES (TILES_X * (IMG_H / TILE))  // 1024
#define SEG 512                            // gaussians per wave-segment
// Half-diagonal of the 8x8 pixel-center extent: 3.5*sqrt(2)/256 = 0.01933495
#define D_HALF 0.019336f                   // strictly above the exact value

// Strict-< sorted-insert ladder; lowest index wins ties (top_k stable order).
#define LADDER(T, G)                                                     \
    if ((T) < v7) {                                                      \
        const bool c0 = (T) < v0, c1 = (T) < v1, c2 = (T) < v2;          \
        const bool c3 = (T) < v3, c4 = (T) < v4, c5 = (T) < v5;          \
        const bool c6 = (T) < v6;                                        \
        v7 = c6 ? v6 : (T);            i7 = c6 ? i6 : (G);               \
        v6 = c6 ? (c5 ? v5 : (T)) : v6; i6 = c6 ? (c5 ? i5 : (G)) : i6;  \
        v5 = c5 ? (c4 ? v4 : (T)) : v5; i5 = c5 ? (c4 ? i4 : (G)) : i5;  \
        v4 = c4 ? (c3 ? v3 : (T)) : v4; i4 = c4 ? (c3 ? i3 : (G)) : i4;  \
        v3 = c3 ? (c2 ? v2 : (T)) : v3; i3 = c3 ? (c2 ? i2 : (G)) : i3;  \
        v2 = c2 ? (c1 ? v1 : (T)) : v2; i2 = c2 ? (c1 ? i1 : (G)) : i2;  \
        v1 = c1 ? (c0 ? v0 : (T)) : v1; i1 = c1 ? (c0 ? i0 : (G)) : i1;  \
        v0 = c0 ? (T) : v0;            i0 = c0 ? (G) : i0;               \
    }

// values-only ladder (screening)
#define VLADDER(T)                                                       \
    if ((T) < v7) {                                                      \
        const bool c0 = (T) < v0, c1 = (T) < v1, c2 = (T) < v2;          \
        const bool c3 = (T) < v3, c4 = (T) < v4, c5 = (T) < v5;          \
        const bool c6 = (T) < v6;                                        \
        v7 = c6 ? v6 : (T);                                              \
        v6 = c6 ? (c5 ? v5 : (T)) : v6;                                  \
        v5 = c5 ? (c4 ? v4 : (T)) : v5;                                  \
        v4 = c4 ? (c3 ? v3 : (T)) : v4;                                  \
        v3 = c3 ? (c2 ? v2 : (T)) : v3;                                  \
        v2 = c2 ? (c1 ? v1 : (T)) : v2;                                  \
        v1 = c1 ? (c0 ? v0 : (T)) : v1;                                  \
        v0 = c0 ? (T) : v0;                                              \
    }

// Compare-exchange on constant-indexed array elems (registers after unroll).
#define CE(a, i, j)                                   \
    { float lo_ = fminf(a[i], a[j]);                  \
      float hi_ = fmaxf(a[i], a[j]);                  \
      a[i] = lo_; a[j] = hi_; }

// A := sorted 8 smallest of (A ∪ B); A,B ascending. Selection-only (exact).
#define MERGE8(A, B)                                  \
    { float t_[8];                                    \
      t_[0] = fminf(A[0], B[7]); t_[1] = fminf(A[1], B[6]); \
      t_[2] = fminf(A[2], B[5]); t_[3] = fminf(A[3], B[4]); \
      t_[4] = fminf(A[4], B[3]); t_[5] = fminf(A[5], B[2]); \
      t_[6] = fminf(A[6], B[1]); t_[7] = fminf(A[7], B[0]); \
      CE(t_,0,4) CE(t_,1,5) CE(t_,2,6) CE(t_,3,7)     \
      CE(t_,0,2) CE(t_,1,3) CE(t_,4,6) CE(t_,5,7)     \
      CE(t_,0,1) CE(t_,2,3) CE(t_,4,5) CE(t_,6,7)     \
      A[0]=t_[0]; A[1]=t_[1]; A[2]=t_[2]; A[3]=t_[3]; \
      A[4]=t_[4]; A[5]=t_[5]; A[6]=t_[6]; A[7]=t_[7]; }

// Single fused kernel: fp32 conservative cull + exact (f64-trig) top-8 + blend.
__launch_bounds__(256)
__global__ void fused_kernel(const float* __restrict__ xy,
                             const float* __restrict__ scale,
                             const float* __restrict__ rot,
                             const float* __restrict__ feat,
                             float* __restrict__ out) {
    __shared__ float rlo[N_GAUSS];            // 8 KB: r(center)-m per gaussian
    __shared__ float wlist[4][8];             // per-wave sorted top-8 of rp
    __shared__ float s_cut;
    __shared__ unsigned short qidx[N_GAUSS];  // 4 KB: per-segment candidates
    __shared__ int qcnt[4];
    __shared__ float          lt[4][8][64];   // 8 KB merge buf
    __shared__ unsigned short li[4][8][64];   // 4 KB

    const int tid  = threadIdx.x;
    const int lane = tid & 63;
    const int w    = tid >> 6;
    const int tile = blockIdx.x;

    // ---------------- Phase A: fp32 screen of all gaussians vs tile center -
    // Approximate trig is fine here: |r_err| <= ~1e-4 << 0.01 cut slack, so
    // the kept set remains a provable superset of every pixel's exact top-8.
    const float cx = (float)((tile & (TILES_X - 1)) * TILE + 4) * (1.0f / IMG_W);
    const float cy = (float)((tile / TILES_X) * TILE + 4) * (1.0f / IMG_H);
    float cur[8];
    {
        float v0 = INFINITY, v1 = INFINITY, v2 = INFINITY, v3 = INFINITY;
        float v4 = INFINITY, v5 = INFINITY, v6 = INFINITY, v7 = INFINITY;
#pragma unroll
        for (int r = 0; r < N_GAUSS / 256; ++r) {
            int g = r * 256 + tid;
            float2 xyg = ((const float2*)xy)[g];
            float2 scg = ((const float2*)scale)[g];
            float  rg  = rot[g];
            float s, c;
            __sincosf(rg, &s, &c);
            float dx = cx - xyg.x;
            float dy = cy - xyg.y;
            float lx = dx * c + dy * s;
            float ly = dy * c - dx * s;
            float a  = lx * scg.x;
            float b  = ly * scg.y;
            float rr = sqrtf(a * a + b * b);
            float m  = fmaxf(scg.x, scg.y) * D_HALF;
            rlo[g]   = rr - m;
            float rp = rr + m;
            VLADDER(rp)
        }
        cur[0] = v0; cur[1] = v1; cur[2] = v2; cur[3] = v3;
        cur[4] = v4; cur[5] = v5; cur[6] = v6; cur[7] = v7;
    }

    // ---------------- Phase B: exact top-8 reduce (register bitonic) -------
#pragma unroll
    for (int m = 1; m < 64; m <<= 1) {
        float oth[8];
#pragma unroll
        for (int k = 0; k < 8; ++k) oth[k] = __shfl_xor(cur[k], m, 64);
        float t_[8];
#pragma unroll
        for (int k = 0; k < 8; ++k) t_[k] = fminf(cur[k], oth[7 - k]);
        CE(t_,0,4) CE(t_,1,5) CE(t_,2,6) CE(t_,3,7)
        CE(t_,0,2) CE(t_,1,3) CE(t_,4,6) CE(t_,5,7)
        CE(t_,0,1) CE(t_,2,3) CE(t_,4,5) CE(t_,6,7)
#pragma unroll
        for (int k = 0; k < 8; ++k) cur[k] = t_[k];
    }
    if (lane == 0) {
#pragma unroll
        for (int k = 0; k < 8; ++k) wlist[w][k] = cur[k];
    }
    __syncthreads();

    if (tid == 0) {
        float A[8], B[8], C2[8], D2[8];
#pragma unroll
        for (int k = 0; k < 8; ++k) {
            A[k]  = wlist[0][k];
            B[k]  = wlist[1][k];
            C2[k] = wlist[2][k];
            D2[k] = wlist[3][k];
        }
        MERGE8(A, B)
        MERGE8(C2, D2)
        MERGE8(A, C2)
        float cut = A[7];
        s_cut = cut + 0.01f + 1e-4f * cut;  // slack >> trig + float error budgets
    }
    __syncthreads();
    const float cut = s_cut;

    // ---------------- Phase C: wave-parallel ordered compaction ------------
    {
        const int segbase = w * SEG;
        unsigned base = 0;
        for (int s2 = 0; s2 < SEG / 64; ++s2) {
            int g = segbase + s2 * 64 + lane;
            bool keep = rlo[g] <= cut;
            unsigned long long mask = __ballot(keep);
            unsigned pos = (unsigned)__popcll(mask & ((1ull << lane) - 1ull));
            if (keep) qidx[segbase + base + pos] = (unsigned short)g;
            base += (unsigned)__popcll(mask);
        }
        if (lane == 0) qcnt[w] = (int)base;
    }
    __syncthreads();

    // ---------------- Phase D: bit-exact top-8 over own segment ------------
    const int pxi = (tile & (TILES_X - 1)) * TILE + (lane & 7);
    const int pyi = (tile / TILES_X) * TILE + (lane >> 3);
    const int p   = pyi * IMG_W + pxi;
    const float px = (pxi + 0.5f) * (1.0f / IMG_W);
    const float py = (pyi + 0.5f) * (1.0f / IMG_H);

    float v0 = INFINITY, v1 = INFINITY, v2 = INFINITY, v3 = INFINITY;
    float v4 = INFINITY, v5 = INFINITY, v6 = INFINITY, v7 = INFINITY;
    int   i0 = 0, i1 = 0, i2 = 0, i3 = 0, i4 = 0, i5 = 0, i6 = 0, i7 = 0;

    {
        const int segbase = w * SEG;
        const int cnt = qcnt[w];
        for (int b = 0; b < cnt; b += 64) {
            int t = b + lane;
            int gg = (t < cnt) ? (int)qidx[segbase + t] : 0;
            // Exact per-candidate params (one candidate per lane).
            float2 xyg = ((const float2*)xy)[gg];
            float2 scg = ((const float2*)scale)[gg];
            double rg  = (double)rot[gg];
            // Correctly-rounded fp32 trig via f64 (bit-identical to prep path).
            float cc = (float)cos(rg);
            float ss = (float)sin(rg);
            int lim = cnt - b; if (lim > 64) lim = 64;
            for (int j = 0; j < lim; ++j) {
                // Broadcast candidate j's params from lane j.
                float ax = __shfl(xyg.x, j, 64);
                float ay = __shfl(xyg.y, j, 64);
                float ac = __shfl(cc,    j, 64);
                float sn = __shfl(ss,    j, 64);
                float bx = __shfl(scg.x, j, 64);
                float by = __shfl(scg.y, j, 64);
                int   g  = __shfl(gg,    j, 64);
                // Bit-exact reference arithmetic (one rounding per op, no fma):
                float dx = __fsub_rn(px, ax);
                float dy = __fsub_rn(py, ay);
                float lx = __fadd_rn(__fmul_rn(dx, ac), __fmul_rn(dy, sn));
                float ly = __fadd_rn(__fmul_rn(-dx, sn), __fmul_rn(dy, ac));
                float aa = __fmul_rn(lx, bx);
                float bb = __fmul_rn(ly, by);
                float t2 = __fadd_rn(__fmul_rn(aa, aa), __fmul_rn(bb, bb));
                LADDER(t2, g)
            }
        }
    }

    lt[w][0][lane] = v0; li[w][0][lane] = (unsigned short)i0;
    lt[w][1][lane] = v1; li[w][1][lane] = (unsigned short)i1;
    lt[w][2][lane] = v2; li[w][2][lane] = (unsigned short)i2;
    lt[w][3][lane] = v3; li[w][3][lane] = (unsigned short)i3;
    lt[w][4][lane] = v4; li[w][4][lane] = (unsigned short)i4;
    lt[w][5][lane] = v5; li[w][5][lane] = (unsigned short)i5;
    lt[w][6][lane] = v6; li[w][6][lane] = (unsigned short)i6;
    lt[w][7][lane] = v7; li[w][7][lane] = (unsigned short)i7;
    __syncthreads();

    if (w == 0) {
        v0 = INFINITY; v1 = INFINITY; v2 = INFINITY; v3 = INFINITY;
        v4 = INFINITY; v5 = INFINITY; v6 = INFINITY; v7 = INFINITY;
        i0 = 0; i1 = 0; i2 = 0; i3 = 0; i4 = 0; i5 = 0; i6 = 0; i7 = 0;
        // Ascending wave order == ascending segment == ascending gaussian
        // index -> identical selection/ordering to the single-stream ladder.
        for (int c = 0; c < 4; ++c) {
#pragma unroll
            for (int k = 0; k < 8; ++k) {
                float t2 = lt[c][k][lane];
                int   g  = (int)li[c][k][lane];
                LADDER(t2, g)
            }
        }
        float w0 = expf(-0.5f * v0), w1 = expf(-0.5f * v1);
        float w2 = expf(-0.5f * v2), w3 = expf(-0.5f * v3);
        float w4 = expf(-0.5f * v4), w5 = expf(-0.5f * v5);
        float w6 = expf(-0.5f * v6), w7 = expf(-0.5f * v7);
        float sum = w0 + w1 + w2 + w3 + w4 + w5 + w6 + w7;
        float inv = 1.0f / (sum + EPS);

        float oc0 = 0.f, oc1 = 0.f, oc2 = 0.f;
#define ACC(K)                                                  \
        {                                                       \
            float al = w##K * inv;                              \
            const float* f = feat + 3 * i##K;                   \
            oc0 = fmaf(al, f[0], oc0);                          \
            oc1 = fmaf(al, f[1], oc1);                          \
            oc2 = fmaf(al, f[2], oc2);                          \
        }
        ACC(0) ACC(1) ACC(2) ACC(3) ACC(4) ACC(5) ACC(6) ACC(7)
#undef ACC

        out[p]            = oc0;
        out[p + NPIX]     = oc1;
        out[p + 2 * NPIX] = oc2;
    }
}

extern "C" void kernel_launch(void* const* d_in, const int* in_sizes, int n_in,
                              void* d_out, int out_size, void* d_ws, size_t ws_size,
                              hipStream_t stream) {
    const float* xy    = (const float*)d_in[0];
    const float* scale = (const float*)d_in[1];
    const float* rot   = (const float*)d_in[2];
    const float* feat  = (const float*)d_in[3];
    float* out = (float*)d_out;

    fused_kernel<<<NTILES, 256, 0, stream>>>(xy, scale, rot, feat, out);
}